// Round 19
// baseline (181.041 us; speedup 1.0000x reference)
//
#include <hip/hip_runtime.h>
#include <hip/hip_bf16.h>

// Shapes
#define NG 16
#define NN 2048
#define NF 32
#define NE 32768
#define IND 65536   // NN*NF
#define HD 512
#define LD 64

typedef unsigned int u32;

// ---------------- GCN part ----------------

// fused: blocks [0,4096): xw = x @ W_gcn
//        blocks [4096,4160): per-chunk deg histogram (atomic-free global) + local pos
//        blocks [4160,6208): prefetch first 64 MB of Wenc into L3
__global__ void k_xwdeg(const float* __restrict__ x, const float* __restrict__ Wg,
                        float* __restrict__ xw, const int* __restrict__ ei,
                        u32* __restrict__ hist4, u32* __restrict__ pos,
                        const float* __restrict__ Wenc){
  int t = threadIdx.x;
  int bid = blockIdx.x;
  if (bid < 4096){
    __shared__ float ws[32][33];
    __shared__ float xsh[8][32];
    for (int i = t; i < 1024; i += 256) ws[i >> 5][i & 31] = Wg[i];
    int base = bid * 8;                 // flat node index (g*NN+n)
    int r = t >> 5, f = t & 31;
    xsh[r][f] = x[(base + r) * 32 + f];
    __syncthreads();
    float acc = 0.f;
    #pragma unroll
    for (int k = 0; k < 32; ++k) acc += xsh[r][k] * ws[k][f];
    xw[(base + r) * 32 + f] = acc;
  } else if (bid < 4160){
    __shared__ u32 hist[2048];
    int db = bid - 4096;                // 64 deg blocks, 4 per graph
    int g = db >> 2, chunk = db & 3;
    int e0 = chunk * 8192;
    const int* dstp = ei + (g * 2 + 1) * NE + e0;
    for (int i = t; i < 2048; i += 256) hist[i] = 0u;
    __syncthreads();
    #pragma unroll
    for (int j = 0; j < 32; ++j)
      atomicAdd(&hist[dstp[j * 256 + t]], 1u);           // LDS atomic (cheap)
    __syncthreads();
    for (int n = t; n < 2048; n += 256){
      u32 v = hist[n];
      hist4[db * 2048 + n] = v;                          // per-chunk counts
      hist[n] = 0u;                                      // reuse as local cursor
    }
    __syncthreads();
    #pragma unroll
    for (int j = 0; j < 32; ++j){
      int e = j * 256 + t;
      int dst = dstp[e];
      u32 loc = atomicAdd(&hist[dst], 1u);               // LDS atomic
      pos[g * NE + e0 + e] = loc;                        // chunk-local position
    }
  } else {
    // prefetch: 2048 blocks x 8192 floats = first 64 MB of Wenc
    int pb = bid - 4160;
    const float4* p = (const float4*)Wenc + (size_t)pb * 2048 + t;
    float acc = 0.f;
    #pragma unroll
    for (int j = 0; j < 8; ++j){
      float4 v = p[j * 256];
      acc += v.x + v.y + v.z + v.w;
    }
    asm volatile("" :: "v"(acc));      // keep loads live, no store
  }
}

// per-graph exclusive prefix sum over summed chunk-hists -> offs, deg, dinv,
// and per-chunk scatter bases basech[g*4+c][n]
__global__ void k_prefix(const u32* __restrict__ hist4, u32* __restrict__ offs,
                         u32* __restrict__ deg, float* __restrict__ dinv,
                         u32* __restrict__ basech){
  int g = blockIdx.x, t = threadIdx.x;      // 16 blocks x 256 threads
  u32 loc[8]; u32 s = 0;
  #pragma unroll
  for (int i = 0; i < 8; ++i){
    int n = t * 8 + i;
    u32 d = hist4[(g * 4 + 0) * 2048 + n] + hist4[(g * 4 + 1) * 2048 + n]
          + hist4[(g * 4 + 2) * 2048 + n] + hist4[(g * 4 + 3) * 2048 + n];
    loc[i] = s; s += d;
  }
  __shared__ u32 bs[256];
  bs[t] = s; __syncthreads();
  for (int d = 1; d < 256; d <<= 1){
    u32 v = (t >= d) ? bs[t - d] : 0u;
    __syncthreads();
    bs[t] += v;
    __syncthreads();
  }
  u32 base = bs[t] - s;                     // exclusive
  #pragma unroll
  for (int i = 0; i < 8; ++i){
    int n = t * 8 + i;
    u32 h0 = hist4[(g * 4 + 0) * 2048 + n];
    u32 h1 = hist4[(g * 4 + 1) * 2048 + n];
    u32 h2 = hist4[(g * 4 + 2) * 2048 + n];
    u32 h3 = hist4[(g * 4 + 3) * 2048 + n];
    u32 d = h0 + h1 + h2 + h3;
    u32 o = g * NE + base + loc[i];
    offs[g * NN + n] = o;
    deg [g * NN + n] = d;
    dinv[g * NN + n] = rsqrtf((float)(d + 1u));  // +1 self loop
    basech[(g * 4 + 0) * 2048 + n] = o;
    basech[(g * 4 + 1) * 2048 + n] = o + h0;
    basech[(g * 4 + 2) * 2048 + n] = o + h0 + h1;
    basech[(g * 4 + 3) * 2048 + n] = o + h0 + h1 + h2;
  }
}

// scatter edges into CSR buckets (no atomics)
__global__ void k_sortedges(const int* __restrict__ ei, const u32* __restrict__ basech,
                            const u32* __restrict__ pos, u32* __restrict__ sorted){
  int idx = blockIdx.x * 256 + threadIdx.x;   // < NG*NE
  int g = idx >> 15, e = idx & (NE - 1);
  int chunk = e >> 13;
  int src = ei[g * 2 * NE + e];
  int dst = ei[(g * 2 + 1) * NE + e];
  sorted[basech[(g * 4 + chunk) * 2048 + dst] + pos[idx]] = (u32)src;
}

// blocks [0,1024): gather; blocks [1024,3072): prefetch second 64 MB of Wenc
__global__ void k_gather(const u32* __restrict__ sorted, const u32* __restrict__ offs,
                         const u32* __restrict__ deg, const float* __restrict__ dinv,
                         const float* __restrict__ xw, const float* __restrict__ bg,
                         float* __restrict__ h, const float* __restrict__ Wenc){
  int t = threadIdx.x;
  int bid = blockIdx.x;
  if (bid >= 1024){
    int pb = bid - 1024;
    const float4* p = (const float4*)Wenc + (size_t)(2048 + pb) * 2048 + t;
    float acc = 0.f;
    #pragma unroll
    for (int j = 0; j < 8; ++j){
      float4 v = p[j * 256];
      acc += v.x + v.y + v.z + v.w;
    }
    asm volatile("" :: "v"(acc));
    return;
  }
  int tid = bid * 256 + t;                    // < NG*NN*8
  int q = tid & 7, n = (tid >> 3) & (NN - 1), g = tid >> 14;
  int gn = g * NN + n;
  u32 o0 = offs[gn];
  u32 cnt = deg[gn];
  float dn = dinv[gn];
  const float4* xw4 = (const float4*)xw;
  float4 acc = make_float4(0.f, 0.f, 0.f, 0.f);
  for (u32 e = 0; e < cnt; ++e){
    u32 src = sorted[o0 + e];
    float c = dinv[g * NN + src] * dn;
    float4 v = xw4[(size_t)(g * NN + src) * 8 + q];
    acc.x += c * v.x; acc.y += c * v.y; acc.z += c * v.z; acc.w += c * v.w;
  }
  float c2 = dn * dn;
  float4 v = xw4[(size_t)gn * 8 + q];
  float4 b = ((const float4*)bg)[q];
  acc.x += c2 * v.x + b.x; acc.y += c2 * v.y + b.y;
  acc.z += c2 * v.z + b.z; acc.w += c2 * v.w + b.w;
  ((float4*)h)[(size_t)gn * 8 + q] = acc;
}

// ---------------- BatchNorm stats ----------------

__global__ void k_bnstat(const float* __restrict__ h, float* __restrict__ pstat){
  int g = blockIdx.x >> 3, s = blockIdx.x & 7;
  int t = threadIdx.x, f = t & 31, r = t >> 5;
  float s1 = 0.f, s2 = 0.f;
  for (int it = 0; it < 32; ++it){
    int n = s * 256 + it * 8 + r;
    float v = h[(size_t)(g * NN + n) * 32 + f];
    s1 += v; s2 += v * v;
  }
  __shared__ float l1[256], l2[256];
  l1[t] = s1; l2[t] = s2;
  __syncthreads();
  if (t < 32){
    float a = 0.f, b = 0.f;
    #pragma unroll
    for (int r2 = 0; r2 < 8; ++r2){ a += l1[r2 * 32 + t]; b += l2[r2 * 32 + t]; }
    pstat[((g * 8 + s) * 32 + t) * 2 + 0] = a;
    pstat[((g * 8 + s) * 32 + t) * 2 + 1] = b;
  }
}

// ---------------- Encoder GEMM (tanh-normalize fused): part[1024][16][512] ----------------

__global__ __launch_bounds__(256) void k_gemvenc(const float* __restrict__ h,
    const float* __restrict__ pstat, const float* __restrict__ gamma,
    const float* __restrict__ beta, const float* __restrict__ B,
    float* __restrict__ part){
  __shared__ float ash[64 * 16];         // stride 16: aligned rows -> ds_read_b128
  __shared__ float ssc[512], ssh[512];
  int t = threadIdx.x;                   // 256 threads
  int k0 = blockIdx.x * 64;              // 1024 chunks of K=64
  for (int i = t; i < 512; i += 256){
    int g = i >> 5, f = i & 31;
    float s1 = 0.f, s2 = 0.f;
    #pragma unroll
    for (int s = 0; s < 8; ++s){
      s1 += pstat[((g * 8 + s) * 32 + f) * 2 + 0];
      s2 += pstat[((g * 8 + s) * 32 + f) * 2 + 1];
    }
    float mean = s1 * (1.f / NN);
    float var  = s2 * (1.f / NN) - mean * mean;
    float sc = gamma[f] * rsqrtf(var + 1e-5f);
    ssc[i] = sc;
    ssh[i] = beta[f] - mean * sc;
  }
  __syncthreads();
  for (int idx = t; idx < 1024; idx += 256){
    int i = idx & 63, g = idx >> 6;
    int f = i & 31;                      // (k0+i)&31 == i&31 since 32 | 64
    float v = h[(size_t)g * IND + k0 + i];
    ash[i * 16 + g] = tanhf(v * ssc[g * 32 + f] + ssh[g * 32 + f]);
  }
  __syncthreads();
  float acc[32];
  #pragma unroll
  for (int i = 0; i < 32; ++i) acc[i] = 0.f;
  const float2* bp = (const float2*)(B + (size_t)k0 * 512) + t;
  for (int kk = 0; kk < 64; kk += 8){
    float2 bv[8];
    #pragma unroll
    for (int u = 0; u < 8; ++u) bv[u] = bp[(size_t)(kk + u) * 256];
    #pragma unroll
    for (int u = 0; u < 8; ++u){
      const float* ap = &ash[(kk + u) * 16];
      #pragma unroll
      for (int m = 0; m < 16; ++m){
        acc[2*m]   += ap[m] * bv[u].x;
        acc[2*m+1] += ap[m] * bv[u].y;
      }
    }
  }
  float* pp = part + (size_t)blockIdx.x * 8192 + t * 2;
  #pragma unroll
  for (int m = 0; m < 16; ++m)
    *(float2*)(pp + (size_t)m * 512) = make_float2(acc[2*m], acc[2*m+1]);
}

// encoder reduce stage1: 1024 chunks -> 8 groups of 128
__global__ void k_encred1(const float* __restrict__ part, float* __restrict__ p2){
  int idx = blockIdx.x * 256 + threadIdx.x;   // < 8*8192
  int out = idx & 8191, grp = idx >> 13;
  const float* p = part + (size_t)grp * 128 * 8192 + out;
  float s = 0.f;
  #pragma unroll 8
  for (int c = 0; c < 128; ++c) s += p[(size_t)c * 8192];
  p2[idx] = s;
}

// henc finalize + heads + reparameterize + decoder layer1, one block per graph
__global__ __launch_bounds__(512) void k_headdec(const float* __restrict__ p2,
    const float* __restrict__ be,
    const float* __restrict__ Wmu, const float* __restrict__ bmu,
    const float* __restrict__ Wlv, const float* __restrict__ blv,
    const float* __restrict__ eps, const float* __restrict__ W1,
    const float* __restrict__ b1, float* __restrict__ hdT, float* __restrict__ outp){
  int g = blockIdx.x, t = threadIdx.x;       // 16 x 512
  __shared__ float hsh[512];
  __shared__ float zsh[64];
  float hv = be[t];
  #pragma unroll
  for (int grp = 0; grp < 8; ++grp) hv += p2[grp * 8192 + g * 512 + t];
  hv = hv > 0.f ? hv : 0.01f * hv;
  hsh[t] = hv;
  __syncthreads();
  int l = t >> 3, r = t & 7;                 // 64 l-slots x 8-way split-K
  float am = 0.f, av = 0.f;
  for (int k = r; k < 512; k += 8){
    float hh = hsh[k];
    am += hh * Wmu[k * 64 + l];
    av += hh * Wlv[k * 64 + l];
  }
  #pragma unroll
  for (int d = 1; d < 8; d <<= 1){
    am += __shfl_xor(am, d);
    av += __shfl_xor(av, d);
  }
  if (r == 0){
    float mean = am + bmu[l];
    float lv   = av + blv[l];
    float z = mean + expf(0.5f * lv) * eps[g * 64 + l];
    zsh[l] = z;
    outp[1048576 + g * 64 + l] = mean;
    outp[1049600 + g * 64 + l] = lv;
  }
  __syncthreads();
  float a = 0.f;
  #pragma unroll
  for (int k = 0; k < 64; ++k) a += zsh[k] * W1[k * 512 + t];
  a += b1[t];
  a = a > 0.f ? a : 0.01f * a;
  hdT[t * 16 + g] = a;
}

// ---------------- Decoder GEMM: full K=512 (8 k-eighth groups), 64-col tiles ----------------

__global__ __launch_bounds__(256) void k_gemvdec(const float* __restrict__ A,    // [512][16] = hdT
                          const float* __restrict__ B,    // [512][65536] = Wd2
                          const float* __restrict__ bias,
                          float* __restrict__ outp){
  __shared__ float ash[8192];          // 32 KB: A, then reduction buffer
  int t = threadIdx.x;                 // 256 threads
  int nt = blockIdx.x;                 // 1024 n-tiles of 64 cols
  for (int i = t; i < 8192; i += 256) ash[i] = A[i];
  __syncthreads();
  int cp = t & 31;                     // float2 col within tile
  int kq = t >> 5;                     // k-eighth (64 rows)
  float acc[32];
  #pragma unroll
  for (int i = 0; i < 32; ++i) acc[i] = 0.f;
  const float2* bp = (const float2*)B + (size_t)(kq * 64) * 32768 + nt * 32 + cp;
  for (int kk = 0; kk < 64; kk += 8){
    float2 bv[8];
    #pragma unroll
    for (int u = 0; u < 8; ++u) bv[u] = bp[(size_t)(kk + u) * 32768];
    #pragma unroll
    for (int u = 0; u < 8; ++u){
      const float* ap = &ash[(kq * 64 + kk + u) * 16];
      #pragma unroll
      for (int m = 0; m < 16; ++m){
        acc[2*m]   += ap[m] * bv[u].x;
        acc[2*m+1] += ap[m] * bv[u].y;
      }
    }
  }
  __syncthreads();                     // done reading A; reuse ash as red[8][32][32]
  #pragma unroll
  for (int m = 0; m < 16; ++m){
    ash[kq * 1024 + (m * 2 + 0) * 32 + cp] = acc[2*m];
    ash[kq * 1024 + (m * 2 + 1) * 32 + cp] = acc[2*m+1];
  }
  __syncthreads();
  // each thread finalizes 2 float2 outputs
  #pragma unroll
  for (int jj = 0; jj < 2; ++jj){
    int idx = t * 2 + jj;              // < 512 float2 outs
    int m = idx >> 5, c = idx & 31;
    float sx = 0.f, sy = 0.f;
    #pragma unroll
    for (int q = 0; q < 8; ++q){
      sx += ash[q * 1024 + (m * 2 + 0) * 32 + c];
      sy += ash[q * 1024 + (m * 2 + 1) * 32 + c];
    }
    float2 bb = ((const float2*)bias)[nt * 32 + c];
    *(float2*)(outp + (size_t)m * 65536 + nt * 64 + c * 2) =
        make_float2(sx + bb.x, sy + bb.y);
  }
}

// ---------------- launch ----------------

extern "C" void kernel_launch(void* const* d_in, const int* in_sizes, int n_in,
                              void* d_out, int out_size, void* d_ws, size_t ws_size,
                              hipStream_t stream){
  const float* x     = (const float*)d_in[0];
  const int*   ei    = (const int*)d_in[1];
  const float* eps   = (const float*)d_in[2];
  const float* Wg    = (const float*)d_in[3];
  const float* bg    = (const float*)d_in[4];
  const float* gamma = (const float*)d_in[5];
  const float* beta  = (const float*)d_in[6];
  const float* Wenc  = (const float*)d_in[7];
  const float* benc  = (const float*)d_in[8];
  const float* Wmu   = (const float*)d_in[9];
  const float* bmu   = (const float*)d_in[10];
  const float* Wlv   = (const float*)d_in[11];
  const float* blv   = (const float*)d_in[12];
  const float* Wd1   = (const float*)d_in[13];
  const float* bd1   = (const float*)d_in[14];
  const float* Wd2   = (const float*)d_in[15];
  const float* bd2   = (const float*)d_in[16];
  float* outp = (float*)d_out;

  char* ws = (char*)d_ws;
  const size_t OFF_XW     = 0;                    // 4 MB
  const size_t OFF_H      = 4194304;              // 4 MB
  const size_t OFF_DEG    = 8388608;              // 128 KB
  const size_t OFF_DINV   = 8519680;              // 128 KB
  const size_t OFF_PSTAT  = 8650752;              // 32 KB
  const size_t OFF_HDT    = 8683520;              // 32 KB
  const size_t OFF_P2     = 8716288;              // 256 KB
  const size_t OFF_POS    = 8978432;              // 2 MB (chunk-local positions)
  const size_t OFF_HIST4  = 11075584;             // 512 KB (per-chunk hists)
  const size_t OFF_BASECH = 11599872;             // 512 KB (per-chunk bases)
  const size_t OFF_PART   = 12124160;             // 32 MB (enc partials)
  // aliases inside PART region: dead before k_gemvenc writes part
  const size_t OFF_SORT   = OFF_PART;             // 2 MB (sorted src)
  const size_t OFF_OFFS   = OFF_PART + 2097152;   // 128 KB (CSR offsets)

  float* xw     = (float*)(ws + OFF_XW);
  float* h      = (float*)(ws + OFF_H);
  u32*   deg    = (u32*)  (ws + OFF_DEG);
  float* dinv   = (float*)(ws + OFF_DINV);
  float* pstat  = (float*)(ws + OFF_PSTAT);
  float* hdT    = (float*)(ws + OFF_HDT);
  float* p2     = (float*)(ws + OFF_P2);
  u32*   pos    = (u32*)  (ws + OFF_POS);
  u32*   hist4  = (u32*)  (ws + OFF_HIST4);
  u32*   basech = (u32*)  (ws + OFF_BASECH);
  float* part   = (float*)(ws + OFF_PART);
  u32*   sorted = (u32*)  (ws + OFF_SORT);
  u32*   offs   = (u32*)  (ws + OFF_OFFS);

  k_xwdeg    <<<6208, 256, 0, stream>>>(x, Wg, xw, ei, hist4, pos, Wenc);
  k_prefix   <<<16,   256, 0, stream>>>(hist4, offs, deg, dinv, basech);
  k_sortedges<<<2048, 256, 0, stream>>>(ei, basech, pos, sorted);
  k_gather   <<<3072, 256, 0, stream>>>(sorted, offs, deg, dinv, xw, bg, h, Wenc);
  k_bnstat   <<<128,  256, 0, stream>>>(h, pstat);

  // encoder: K=65536 in 1024 chunks of 64 (tanh-norm fused), N=512
  k_gemvenc  <<<1024, 256, 0, stream>>>(h, pstat, gamma, beta, Wenc, part);
  k_encred1  <<<256,  256, 0, stream>>>(part, p2);

  k_headdec  <<<16, 512, 0, stream>>>(p2, benc, Wmu, bmu, Wlv, blv, eps, Wd1, bd1, hdT, outp);

  // decoder: full K=512 per block, 1024 tiles of 64 cols, direct write + bias
  k_gemvdec  <<<1024, 256, 0, stream>>>(hdT, Wd2, bd2, outp);
}

// Round 20
// 153.252 us; speedup vs baseline: 1.1813x; 1.1813x over previous
//
#include <hip/hip_runtime.h>
#include <hip/hip_bf16.h>

// Shapes
#define NG 16
#define NN 2048
#define NF 32
#define NE 32768
#define IND 65536   // NN*NF
#define HD 512
#define LD 64

typedef unsigned int u32;

// ---------------- GCN part ----------------

// fused: blocks [0,4096): xw = x @ W_gcn
//        blocks [4096,4160): per-chunk deg histogram (atomic-free global) + local pos
__global__ void k_xwdeg(const float* __restrict__ x, const float* __restrict__ Wg,
                        float* __restrict__ xw, const int* __restrict__ ei,
                        u32* __restrict__ hist4, u32* __restrict__ pos){
  int t = threadIdx.x;
  int bid = blockIdx.x;
  if (bid < 4096){
    __shared__ float ws[32][33];
    __shared__ float xsh[8][32];
    for (int i = t; i < 1024; i += 256) ws[i >> 5][i & 31] = Wg[i];
    int base = bid * 8;                 // flat node index (g*NN+n)
    int r = t >> 5, f = t & 31;
    xsh[r][f] = x[(base + r) * 32 + f];
    __syncthreads();
    float acc = 0.f;
    #pragma unroll
    for (int k = 0; k < 32; ++k) acc += xsh[r][k] * ws[k][f];
    xw[(base + r) * 32 + f] = acc;
  } else {
    __shared__ u32 hist[2048];
    int db = bid - 4096;                // 64 deg blocks, 4 per graph
    int g = db >> 2, chunk = db & 3;
    int e0 = chunk * 8192;
    const int* dstp = ei + (g * 2 + 1) * NE + e0;
    for (int i = t; i < 2048; i += 256) hist[i] = 0u;
    __syncthreads();
    #pragma unroll
    for (int j = 0; j < 32; ++j)
      atomicAdd(&hist[dstp[j * 256 + t]], 1u);           // LDS atomic (cheap)
    __syncthreads();
    for (int n = t; n < 2048; n += 256){
      u32 v = hist[n];
      hist4[db * 2048 + n] = v;                          // per-chunk counts
      hist[n] = 0u;                                      // reuse as local cursor
    }
    __syncthreads();
    #pragma unroll
    for (int j = 0; j < 32; ++j){
      int e = j * 256 + t;
      int dst = dstp[e];
      u32 loc = atomicAdd(&hist[dst], 1u);               // LDS atomic
      pos[g * NE + e0 + e] = loc;                        // chunk-local position
    }
  }
}

// per-graph exclusive prefix sum over summed chunk-hists -> offs, deg, dinv,
// and per-chunk scatter bases basech[g*4+c][n]
__global__ void k_prefix(const u32* __restrict__ hist4, u32* __restrict__ offs,
                         u32* __restrict__ deg, float* __restrict__ dinv,
                         u32* __restrict__ basech){
  int g = blockIdx.x, t = threadIdx.x;      // 16 blocks x 256 threads
  u32 loc[8]; u32 s = 0;
  #pragma unroll
  for (int i = 0; i < 8; ++i){
    int n = t * 8 + i;
    u32 d = hist4[(g * 4 + 0) * 2048 + n] + hist4[(g * 4 + 1) * 2048 + n]
          + hist4[(g * 4 + 2) * 2048 + n] + hist4[(g * 4 + 3) * 2048 + n];
    loc[i] = s; s += d;
  }
  __shared__ u32 bs[256];
  bs[t] = s; __syncthreads();
  for (int d = 1; d < 256; d <<= 1){
    u32 v = (t >= d) ? bs[t - d] : 0u;
    __syncthreads();
    bs[t] += v;
    __syncthreads();
  }
  u32 base = bs[t] - s;                     // exclusive
  #pragma unroll
  for (int i = 0; i < 8; ++i){
    int n = t * 8 + i;
    u32 h0 = hist4[(g * 4 + 0) * 2048 + n];
    u32 h1 = hist4[(g * 4 + 1) * 2048 + n];
    u32 h2 = hist4[(g * 4 + 2) * 2048 + n];
    u32 h3 = hist4[(g * 4 + 3) * 2048 + n];
    u32 d = h0 + h1 + h2 + h3;
    u32 o = g * NE + base + loc[i];
    offs[g * NN + n] = o;
    deg [g * NN + n] = d;
    dinv[g * NN + n] = rsqrtf((float)(d + 1u));  // +1 self loop
    basech[(g * 4 + 0) * 2048 + n] = o;
    basech[(g * 4 + 1) * 2048 + n] = o + h0;
    basech[(g * 4 + 2) * 2048 + n] = o + h0 + h1;
    basech[(g * 4 + 3) * 2048 + n] = o + h0 + h1 + h2;
  }
}

// scatter edges into CSR buckets (no atomics)
__global__ void k_sortedges(const int* __restrict__ ei, const u32* __restrict__ basech,
                            const u32* __restrict__ pos, u32* __restrict__ sorted){
  int idx = blockIdx.x * 256 + threadIdx.x;   // < NG*NE
  int g = idx >> 15, e = idx & (NE - 1);
  int chunk = e >> 13;
  int src = ei[g * 2 * NE + e];
  int dst = ei[(g * 2 + 1) * NE + e];
  sorted[basech[(g * 4 + chunk) * 2048 + dst] + pos[idx]] = (u32)src;
}

// gather: h[g][n][f] = sum_{src->n} dinv[src]*dinv[n]*xw[src][f] + dinv[n]^2*xw[n][f] + bg[f]
// 8 threads per node (one float4 quad each) for max TLP on the dependent-load chain
__global__ void k_gather(const u32* __restrict__ sorted, const u32* __restrict__ offs,
                         const u32* __restrict__ deg, const float* __restrict__ dinv,
                         const float* __restrict__ xw, const float* __restrict__ bg,
                         float* __restrict__ h){
  int tid = blockIdx.x * 256 + threadIdx.x;   // < NG*NN*8
  int q = tid & 7, n = (tid >> 3) & (NN - 1), g = tid >> 14;
  int gn = g * NN + n;
  u32 o0 = offs[gn];
  u32 cnt = deg[gn];
  float dn = dinv[gn];
  const float4* xw4 = (const float4*)xw;
  float4 acc = make_float4(0.f, 0.f, 0.f, 0.f);
  for (u32 e = 0; e < cnt; ++e){
    u32 src = sorted[o0 + e];
    float c = dinv[g * NN + src] * dn;
    float4 v = xw4[(size_t)(g * NN + src) * 8 + q];
    acc.x += c * v.x; acc.y += c * v.y; acc.z += c * v.z; acc.w += c * v.w;
  }
  float c2 = dn * dn;
  float4 v = xw4[(size_t)gn * 8 + q];
  float4 b = ((const float4*)bg)[q];
  acc.x += c2 * v.x + b.x; acc.y += c2 * v.y + b.y;
  acc.z += c2 * v.z + b.z; acc.w += c2 * v.w + b.w;
  ((float4*)h)[(size_t)gn * 8 + q] = acc;
}

// ---------------- BatchNorm stats ----------------

__global__ void k_bnstat(const float* __restrict__ h, float* __restrict__ pstat){
  int g = blockIdx.x >> 3, s = blockIdx.x & 7;
  int t = threadIdx.x, f = t & 31, r = t >> 5;
  float s1 = 0.f, s2 = 0.f;
  for (int it = 0; it < 32; ++it){
    int n = s * 256 + it * 8 + r;
    float v = h[(size_t)(g * NN + n) * 32 + f];
    s1 += v; s2 += v * v;
  }
  __shared__ float l1[256], l2[256];
  l1[t] = s1; l2[t] = s2;
  __syncthreads();
  if (t < 32){
    float a = 0.f, b = 0.f;
    #pragma unroll
    for (int r2 = 0; r2 < 8; ++r2){ a += l1[r2 * 32 + t]; b += l2[r2 * 32 + t]; }
    pstat[((g * 8 + s) * 32 + t) * 2 + 0] = a;
    pstat[((g * 8 + s) * 32 + t) * 2 + 1] = b;
  }
}

// ---------------- Encoder GEMM (tanh-normalize fused): part[1024][16][512] ----------------

__global__ __launch_bounds__(256) void k_gemvenc(const float* __restrict__ h,
    const float* __restrict__ pstat, const float* __restrict__ gamma,
    const float* __restrict__ beta, const float* __restrict__ B,
    float* __restrict__ part){
  __shared__ float ash[64 * 16];         // stride 16: aligned rows -> ds_read_b128
  __shared__ float ssc[512], ssh[512];
  int t = threadIdx.x;                   // 256 threads
  int k0 = blockIdx.x * 64;              // 1024 chunks of K=64
  for (int i = t; i < 512; i += 256){
    int g = i >> 5, f = i & 31;
    float s1 = 0.f, s2 = 0.f;
    #pragma unroll
    for (int s = 0; s < 8; ++s){
      s1 += pstat[((g * 8 + s) * 32 + f) * 2 + 0];
      s2 += pstat[((g * 8 + s) * 32 + f) * 2 + 1];
    }
    float mean = s1 * (1.f / NN);
    float var  = s2 * (1.f / NN) - mean * mean;
    float sc = gamma[f] * rsqrtf(var + 1e-5f);
    ssc[i] = sc;
    ssh[i] = beta[f] - mean * sc;
  }
  __syncthreads();
  for (int idx = t; idx < 1024; idx += 256){
    int i = idx & 63, g = idx >> 6;
    int f = i & 31;                      // (k0+i)&31 == i&31 since 32 | 64
    float v = h[(size_t)g * IND + k0 + i];
    ash[i * 16 + g] = tanhf(v * ssc[g * 32 + f] + ssh[g * 32 + f]);
  }
  __syncthreads();
  float acc[32];
  #pragma unroll
  for (int i = 0; i < 32; ++i) acc[i] = 0.f;
  const float2* bp = (const float2*)(B + (size_t)k0 * 512) + t;
  for (int kk = 0; kk < 64; kk += 8){
    float2 bv[8];
    #pragma unroll
    for (int u = 0; u < 8; ++u) bv[u] = bp[(size_t)(kk + u) * 256];
    #pragma unroll
    for (int u = 0; u < 8; ++u){
      const float* ap = &ash[(kk + u) * 16];
      #pragma unroll
      for (int m = 0; m < 16; ++m){
        acc[2*m]   += ap[m] * bv[u].x;
        acc[2*m+1] += ap[m] * bv[u].y;
      }
    }
  }
  float* pp = part + (size_t)blockIdx.x * 8192 + t * 2;
  #pragma unroll
  for (int m = 0; m < 16; ++m)
    *(float2*)(pp + (size_t)m * 512) = make_float2(acc[2*m], acc[2*m+1]);
}

// encoder reduce stage1: 1024 chunks -> 8 groups of 128
__global__ void k_encred1(const float* __restrict__ part, float* __restrict__ p2){
  int idx = blockIdx.x * 256 + threadIdx.x;   // < 8*8192
  int out = idx & 8191, grp = idx >> 13;
  const float* p = part + (size_t)grp * 128 * 8192 + out;
  float s = 0.f;
  #pragma unroll 8
  for (int c = 0; c < 128; ++c) s += p[(size_t)c * 8192];
  p2[idx] = s;
}

// henc finalize + heads + reparameterize + decoder layer1, one block per graph
__global__ __launch_bounds__(512) void k_headdec(const float* __restrict__ p2,
    const float* __restrict__ be,
    const float* __restrict__ Wmu, const float* __restrict__ bmu,
    const float* __restrict__ Wlv, const float* __restrict__ blv,
    const float* __restrict__ eps, const float* __restrict__ W1,
    const float* __restrict__ b1, float* __restrict__ hdT, float* __restrict__ outp){
  int g = blockIdx.x, t = threadIdx.x;       // 16 x 512
  __shared__ float hsh[512];
  __shared__ float zsh[64];
  float hv = be[t];
  #pragma unroll
  for (int grp = 0; grp < 8; ++grp) hv += p2[grp * 8192 + g * 512 + t];
  hv = hv > 0.f ? hv : 0.01f * hv;
  hsh[t] = hv;
  __syncthreads();
  int l = t >> 3, r = t & 7;                 // 64 l-slots x 8-way split-K
  float am = 0.f, av = 0.f;
  for (int k = r; k < 512; k += 8){
    float hh = hsh[k];
    am += hh * Wmu[k * 64 + l];
    av += hh * Wlv[k * 64 + l];
  }
  #pragma unroll
  for (int d = 1; d < 8; d <<= 1){
    am += __shfl_xor(am, d);
    av += __shfl_xor(av, d);
  }
  if (r == 0){
    float mean = am + bmu[l];
    float lv   = av + blv[l];
    float z = mean + expf(0.5f * lv) * eps[g * 64 + l];
    zsh[l] = z;
    outp[1048576 + g * 64 + l] = mean;
    outp[1049600 + g * 64 + l] = lv;
  }
  __syncthreads();
  float a = 0.f;
  #pragma unroll
  for (int k = 0; k < 64; ++k) a += zsh[k] * W1[k * 512 + t];
  a += b1[t];
  a = a > 0.f ? a : 0.01f * a;
  hdT[t * 16 + g] = a;
}

// ---------------- Decoder GEMM: full K=512 (8 k-eighth groups), 64-col tiles ----------------

__global__ __launch_bounds__(256) void k_gemvdec(const float* __restrict__ A,    // [512][16] = hdT
                          const float* __restrict__ B,    // [512][65536] = Wd2
                          const float* __restrict__ bias,
                          float* __restrict__ outp){
  __shared__ float ash[8192];          // 32 KB: A, then reduction buffer
  int t = threadIdx.x;                 // 256 threads
  int nt = blockIdx.x;                 // 1024 n-tiles of 64 cols
  for (int i = t; i < 8192; i += 256) ash[i] = A[i];
  __syncthreads();
  int cp = t & 31;                     // float2 col within tile
  int kq = t >> 5;                     // k-eighth (64 rows)
  float acc[32];
  #pragma unroll
  for (int i = 0; i < 32; ++i) acc[i] = 0.f;
  const float2* bp = (const float2*)B + (size_t)(kq * 64) * 32768 + nt * 32 + cp;
  for (int kk = 0; kk < 64; kk += 8){
    float2 bv[8];
    #pragma unroll
    for (int u = 0; u < 8; ++u) bv[u] = bp[(size_t)(kk + u) * 32768];
    #pragma unroll
    for (int u = 0; u < 8; ++u){
      const float* ap = &ash[(kq * 64 + kk + u) * 16];
      #pragma unroll
      for (int m = 0; m < 16; ++m){
        acc[2*m]   += ap[m] * bv[u].x;
        acc[2*m+1] += ap[m] * bv[u].y;
      }
    }
  }
  __syncthreads();                     // done reading A; reuse ash as red[8][32][32]
  #pragma unroll
  for (int m = 0; m < 16; ++m){
    ash[kq * 1024 + (m * 2 + 0) * 32 + cp] = acc[2*m];
    ash[kq * 1024 + (m * 2 + 1) * 32 + cp] = acc[2*m+1];
  }
  __syncthreads();
  // each thread finalizes 2 float2 outputs
  #pragma unroll
  for (int jj = 0; jj < 2; ++jj){
    int idx = t * 2 + jj;              // < 512 float2 outs
    int m = idx >> 5, c = idx & 31;
    float sx = 0.f, sy = 0.f;
    #pragma unroll
    for (int q = 0; q < 8; ++q){
      sx += ash[q * 1024 + (m * 2 + 0) * 32 + c];
      sy += ash[q * 1024 + (m * 2 + 1) * 32 + c];
    }
    float2 bb = ((const float2*)bias)[nt * 32 + c];
    *(float2*)(outp + (size_t)m * 65536 + nt * 64 + c * 2) =
        make_float2(sx + bb.x, sy + bb.y);
  }
}

// ---------------- launch ----------------

extern "C" void kernel_launch(void* const* d_in, const int* in_sizes, int n_in,
                              void* d_out, int out_size, void* d_ws, size_t ws_size,
                              hipStream_t stream){
  const float* x     = (const float*)d_in[0];
  const int*   ei    = (const int*)d_in[1];
  const float* eps   = (const float*)d_in[2];
  const float* Wg    = (const float*)d_in[3];
  const float* bg    = (const float*)d_in[4];
  const float* gamma = (const float*)d_in[5];
  const float* beta  = (const float*)d_in[6];
  const float* Wenc  = (const float*)d_in[7];
  const float* benc  = (const float*)d_in[8];
  const float* Wmu   = (const float*)d_in[9];
  const float* bmu   = (const float*)d_in[10];
  const float* Wlv   = (const float*)d_in[11];
  const float* blv   = (const float*)d_in[12];
  const float* Wd1   = (const float*)d_in[13];
  const float* bd1   = (const float*)d_in[14];
  const float* Wd2   = (const float*)d_in[15];
  const float* bd2   = (const float*)d_in[16];
  float* outp = (float*)d_out;

  char* ws = (char*)d_ws;
  const size_t OFF_XW     = 0;                    // 4 MB
  const size_t OFF_H      = 4194304;              // 4 MB
  const size_t OFF_DEG    = 8388608;              // 128 KB
  const size_t OFF_DINV   = 8519680;              // 128 KB
  const size_t OFF_PSTAT  = 8650752;              // 32 KB
  const size_t OFF_HDT    = 8683520;              // 32 KB
  const size_t OFF_P2     = 8716288;              // 256 KB
  const size_t OFF_POS    = 8978432;              // 2 MB (chunk-local positions)
  const size_t OFF_HIST4  = 11075584;             // 512 KB (per-chunk hists)
  const size_t OFF_BASECH = 11599872;             // 512 KB (per-chunk bases)
  const size_t OFF_PART   = 12124160;             // 32 MB (enc partials)
  // aliases inside PART region: dead before k_gemvenc writes part
  const size_t OFF_SORT   = OFF_PART;             // 2 MB (sorted src)
  const size_t OFF_OFFS   = OFF_PART + 2097152;   // 128 KB (CSR offsets)

  float* xw     = (float*)(ws + OFF_XW);
  float* h      = (float*)(ws + OFF_H);
  u32*   deg    = (u32*)  (ws + OFF_DEG);
  float* dinv   = (float*)(ws + OFF_DINV);
  float* pstat  = (float*)(ws + OFF_PSTAT);
  float* hdT    = (float*)(ws + OFF_HDT);
  float* p2     = (float*)(ws + OFF_P2);
  u32*   pos    = (u32*)  (ws + OFF_POS);
  u32*   hist4  = (u32*)  (ws + OFF_HIST4);
  u32*   basech = (u32*)  (ws + OFF_BASECH);
  float* part   = (float*)(ws + OFF_PART);
  u32*   sorted = (u32*)  (ws + OFF_SORT);
  u32*   offs   = (u32*)  (ws + OFF_OFFS);

  k_xwdeg    <<<4160, 256, 0, stream>>>(x, Wg, xw, ei, hist4, pos);
  k_prefix   <<<16,   256, 0, stream>>>(hist4, offs, deg, dinv, basech);
  k_sortedges<<<2048, 256, 0, stream>>>(ei, basech, pos, sorted);
  k_gather   <<<1024, 256, 0, stream>>>(sorted, offs, deg, dinv, xw, bg, h);
  k_bnstat   <<<128,  256, 0, stream>>>(h, pstat);

  // encoder: K=65536 in 1024 chunks of 64 (tanh-norm fused), N=512
  k_gemvenc  <<<1024, 256, 0, stream>>>(h, pstat, gamma, beta, Wenc, part);
  k_encred1  <<<256,  256, 0, stream>>>(part, p2);

  k_headdec  <<<16, 512, 0, stream>>>(p2, benc, Wmu, bmu, Wlv, blv, eps, Wd1, bd1, hdT, outp);

  // decoder: full K=512 per block, 1024 tiles of 64 cols, direct write + bias
  k_gemvdec  <<<1024, 256, 0, stream>>>(hdT, Wd2, bd2, outp);
}